// Round 7
// baseline (448.197 us; speedup 1.0000x reference)
//
#include <hip/hip_runtime.h>

typedef unsigned short ushort_t;
typedef unsigned int uint_t;
typedef __attribute__((ext_vector_type(8))) short short8;
typedef __attribute__((ext_vector_type(4))) float f32x4;

#define PAD 40   // staging LDS elems per pixel/co row: bank stride 20 -> 2-way (free)

__device__ __forceinline__ ushort_t f2bf(float f) {
    uint_t u = __float_as_uint(f);
    u = (u + 0x7FFFu + ((u >> 16) & 1u)) >> 16;
    return (ushort_t)u;
}
__device__ __forceinline__ float bf2f(ushort_t h) {
    return __uint_as_float(((uint_t)h) << 16);
}

__device__ __forceinline__ void red_stats(float& s, float& ss) {
    s += __shfl_xor(s, 16); ss += __shfl_xor(ss, 16);
    s += __shfl_xor(s, 32); ss += __shfl_xor(ss, 32);
    s += __shfl_xor(s, 1);  ss += __shfl_xor(ss, 1);
    s += __shfl_xor(s, 2);  ss += __shfl_xor(ss, 2);
    s += __shfl_xor(s, 4);  ss += __shfl_xor(ss, 4);
}

// normalize 8 bf16 channels with (scale,shift) from LDS table + ReLU
__device__ __forceinline__ uint4 gn8(uint4 v, const float2* ss) {
    uint_t u[4] = {v.x, v.y, v.z, v.w};
    uint_t r[4];
#pragma unroll
    for (int p = 0; p < 4; ++p) {
        float2 s0 = ss[2 * p], s1 = ss[2 * p + 1];
        float f0 = fmaxf(bf2f((ushort_t)(u[p] & 0xffffu)) * s0.x + s0.y, 0.f);
        float f1 = fmaxf(bf2f((ushort_t)(u[p] >> 16)) * s1.x + s1.y, 0.f);
        r[p] = (uint_t)f2bf(f0) | ((uint_t)f2bf(f1) << 16);
    }
    return make_uint4(r[0], r[1], r[2], r[3]);
}

// fill per-channel (scale, shift) LDS table from per-block partial (sum, sumsq)
// stats. Deterministic fixed-order reduction over NPB partials.
template<int C, int NPB>
__device__ __forceinline__ void fill_ss(float2* sshare, const float2* __restrict__ pin,
                                        const float* __restrict__ gamma,
                                        const float* __restrict__ beta,
                                        int b, float invC, int tid) {
    for (int c = tid; c < C; c += 256) {
        const float2* p = pin + ((size_t)b * (C / 8) + (c >> 3)) * NPB;
        float s = 0.f, ss = 0.f;
#pragma unroll 8
        for (int i = 0; i < NPB; ++i) { s += p[i].x; ss += p[i].y; }
        float mean = s * invC;
        float rstd = rsqrtf(ss * invC - mean * mean + 1e-5f);
        float sc = gamma[c] * rstd;
        sshare[c] = make_float2(sc, beta[c] - mean * sc);
    }
}

// ---------------------------------------------------------------------------
// Weight packing (one merged kernel)
// ---------------------------------------------------------------------------
template<int CIN, int COUT>
__device__ __forceinline__ void pack3(const float* __restrict__ W, ushort_t* __restrict__ wp, int idx) {
    int kk = idx & 31;
    int t = idx >> 5;
    int co = t % COUT; t /= COUT;
    int tap = t % 9;
    int cib = t / 9;
    wp[idx] = f2bf(W[(co * CIN + cib * 32 + kk) * 9 + tap]);
}

__device__ __forceinline__ void pack2p(const float* __restrict__ W2, ushort_t* __restrict__ wp, int idx) {
    int kk = idx & 31;
    int co = (idx >> 5) & 127;
    int tap = (idx >> 12) & 3;
    int cib = idx >> 14;
    int p = cib >> 2, q = (cib >> 1) & 1, chalf = cib & 1;
    int kh = 2 * (tap >> 1) + p - 1;
    int kw = 2 * (tap & 1) + q - 1;
    float v = 0.f;
    if (kh >= 0 && kh < 3 && kw >= 0 && kw < 3)
        v = W2[(co * 64 + chalf * 32 + kk) * 9 + kh * 3 + kw];
    wp[idx] = f2bf(v);
}

__device__ __forceinline__ void packt(const float* __restrict__ Wt, ushort_t* __restrict__ wp, int idx) {
    int kk = idx & 31;
    int t = idx >> 5;
    int co = t & 63; t >>= 6;
    int tap = t & 3; t >>= 2;
    int cib = t & 3;
    int ph = t >> 2;
    int rs = tap >> 1, cs = tap & 1;
    int eh = ph >> 1, ew = ph & 1;
    int kh = eh ? (rs ? 0 : 2) : (rs ? 1 : 3);
    int kw = ew ? (cs ? 0 : 2) : (cs ? 1 : 3);
    wp[idx] = f2bf(Wt[((cib * 32 + kk) * 64 + co) * 16 + kh * 4 + kw]);
}

__global__ __launch_bounds__(256) void pack_all(const float* __restrict__ W1,
                                                const float* __restrict__ W2,
                                                const float* __restrict__ W3,
                                                const float* __restrict__ W4,
                                                const float* __restrict__ Wt,
                                                const float* __restrict__ W6,
                                                ushort_t* __restrict__ WP) {
    int idx = blockIdx.x * 256 + threadIdx.x;
    if (idx < 18432)        pack3<32, 64>(W1, WP, idx);
    else if (idx < 149504)  pack2p(W2, WP + 18432, idx - 18432);
    else if (idx < 444416)  pack3<128, 256>(W3, WP + 149504, idx - 149504);
    else if (idx < 739328)  pack3<256, 128>(W4, WP + 444416, idx - 444416);
    else if (idx < 870400)  packt(Wt, WP + 739328, idx - 739328);
    else if (idx < 879616)  pack3<64, 16>(W6, WP + 870400, idx - 870400);
}

// ---------------------------------------------------------------------------
// DWT: x NCHW fp32 [16,8,256,256] -> NHWC bf16 [16,128,128,32]
// ---------------------------------------------------------------------------
__global__ __launch_bounds__(256) void dwt_nhwc(const float* __restrict__ x,
                                                const float* __restrict__ Kd,
                                                ushort_t* __restrict__ out) {
    int idx = blockIdx.x * 256 + threadIdx.x;
    int w = idx & 127, h = (idx >> 7) & 127, b = idx >> 14;
    float k[16];
#pragma unroll
    for (int i = 0; i < 16; ++i) k[i] = Kd[i];
    const float* xb = x + (size_t)b * 8 * 65536;
    uint_t uu[16];
#pragma unroll
    for (int ci = 0; ci < 8; ++ci) {
        const float* p = xb + ci * 65536 + (2 * h) * 256 + 2 * w;
        float2 r0 = *(const float2*)p;
        float2 r1 = *(const float2*)(p + 256);
        ushort_t o[4];
#pragma unroll
        for (int sb = 0; sb < 4; ++sb) {
            float v = r0.x * k[sb*4] + r0.y * k[sb*4+1] + r1.x * k[sb*4+2] + r1.y * k[sb*4+3];
            o[sb] = f2bf(v);
        }
        uu[ci*2]   = (uint_t)o[0] | ((uint_t)o[1] << 16);
        uu[ci*2+1] = (uint_t)o[2] | ((uint_t)o[3] << 16);
    }
    uint4* dst = (uint4*)(out + (size_t)idx * 32);
    dst[0] = make_uint4(uu[0], uu[1], uu[2], uu[3]);
    dst[1] = make_uint4(uu[4], uu[5], uu[6], uu[7]);
    dst[2] = make_uint4(uu[8], uu[9], uu[10], uu[11]);
    dst[3] = make_uint4(uu[12], uu[13], uu[14], uu[15]);
}

// ---------------------------------------------------------------------------
// IDWT: in NHWC bf16 [16,128,128,16] -> out NCHW fp32 [16,4,256,256]
// ---------------------------------------------------------------------------
__global__ __launch_bounds__(256) void idwt_nhwc(const ushort_t* __restrict__ cin,
                                                 const float* __restrict__ Kr,
                                                 float* __restrict__ out) {
    int idx = blockIdx.x * 256 + threadIdx.x;
    int w = idx & 127, h = (idx >> 7) & 127, b = idx >> 14;
    float k[16];
#pragma unroll
    for (int i = 0; i < 16; ++i) k[i] = Kr[i];
    const uint4* pv = (const uint4*)(cin + (size_t)idx * 16);
    uint4 v0 = pv[0], v1 = pv[1];
    uint_t uw[8] = {v0.x, v0.y, v0.z, v0.w, v1.x, v1.y, v1.z, v1.w};
    float cs[16];
#pragma unroll
    for (int i = 0; i < 8; ++i) {
        cs[2*i]   = bf2f((ushort_t)(uw[i] & 0xffffu));
        cs[2*i+1] = bf2f((ushort_t)(uw[i] >> 16));
    }
#pragma unroll
    for (int c = 0; c < 4; ++c) {
        float y00 = 0, y01 = 0, y10 = 0, y11 = 0;
#pragma unroll
        for (int sb = 0; sb < 4; ++sb) {
            float v = cs[c * 4 + sb];
            y00 += v * k[sb*4];   y01 += v * k[sb*4+1];
            y10 += v * k[sb*4+2]; y11 += v * k[sb*4+3];
        }
        float* ob = out + ((size_t)(b * 4 + c) * 256 + 2 * h) * 256 + 2 * w;
        *(float2*)ob = make_float2(y00, y01);
        *(float2*)(ob + 256) = make_float2(y10, y11);
    }
}

// ---------------------------------------------------------------------------
// Implicit-GEMM 3x3 stride-1 conv, MFMA 16x16x32, XCD-swizzled grid.
// Activations are channel-blocked NHWC: [B, C/64, H, W, 64] (C<64 -> [B,1,H,W,C]).
// Each block writes one fully-contiguous 32KB output span (no line sharing).
// ---------------------------------------------------------------------------
template<int CIN, int COUT, int H, int W, bool STATS, bool GNIN, int NPBI>
__global__ __launch_bounds__(256, 2) void conv_mfma(const ushort_t* __restrict__ in,
                                                    const ushort_t* __restrict__ wp,
                                                    const float* __restrict__ bias,
                                                    ushort_t* __restrict__ outp,
                                                    float2* __restrict__ pstats_out,
                                                    const float2* __restrict__ pstats_in,
                                                    const float* __restrict__ gamma,
                                                    const float* __restrict__ beta,
                                                    float invC) {
    constexpr int NT = (COUT < 64) ? COUT : 64;
    constexpr int NF = NT / 16;
    constexpr int NCB = CIN / 32;
    constexpr int CSTR = (CIN < 64) ? CIN : 64;   // input channel-block stride
    constexpr int NBI = CIN / CSTR;               // input channel-blocks
    constexpr int SUB = CSTR / 32;                // 32-chunks per input block
    constexpr int NBO = COUT / NT;                // output channel-blocks
    constexpr int IW = 66, NRI = 6;
    constexpr int AITER = NRI * IW * 4;
    constexpr int CA = (AITER + 255) / 256;
    constexpr int BITER = 9 * NT * 4;
    constexpr int CB = (BITER + 255) / 256;
    constexpr int NW = W / 64, NH = H / 4;
    constexpr int PB = NBO * NW * NH;
    constexpr int NPBO = NH * NW;
    constexpr int EP = NT + 8;

    __shared__ ushort_t smem[NRI * IW * PAD + 9 * NT * PAD];
    __shared__ float2 sred[4][8];
    __shared__ float2 sshare[CIN];
    ushort_t* lA = smem;
    ushort_t* lB = smem + NRI * IW * PAD;
    ushort_t* lE = smem;

    // XCD-locality decode: xcd = bid&7 -> batch group {xcd, xcd+8}
    int bid = blockIdx.x;
    int xcd = bid & 7;
    int rest = bid >> 3;
    int half = rest / PB;
    int local = rest - half * PB;
    int b = xcd + 8 * half;
    int ht = local % NH; local /= NH;
    int wt = local % NW; local /= NW;
    int nb = local;
    int h0 = ht * 4, w0 = wt * 64, n0 = nb * NT;
    int tid = threadIdx.x;
    int lane = tid & 63, wid = tid >> 6;
    int nl = lane & 15, quad = lane >> 4, ql = quad * 8;

    if (GNIN) {
        fill_ss<CIN, NPBI>(sshare, pstats_in, gamma, beta, b, invC, tid);
        __syncthreads();
    }

    int ga[CA], la[CA], pr[CA];
#pragma unroll
    for (int r = 0; r < CA; ++r) {
        int i = tid + r * 256;
        ga[r] = -1; la[r] = 0; pr[r] = 0;
        if (i < AITER) {
            int tr = i / (IW * 4); int rem = i - tr * (IW * 4);
            int p = rem >> 2, part = rem & 3;
            la[r] = (tr * IW + p) * PAD + part * 8;
            pr[r] = part;
            int ih = h0 - 1 + tr, iw = w0 - 1 + p;
            if ((unsigned)ih < (unsigned)H && (unsigned)iw < (unsigned)W)
                ga[r] = (ih * W + iw) * CSTR + part * 8;
        }
    }
    int gb[CB], lb[CB];
#pragma unroll
    for (int r = 0; r < CB; ++r) {
        int i = tid + r * 256;
        gb[r] = -1; lb[r] = 0;
        if (i < BITER) {
            int tap = i / (NT * 4); int rem = i - tap * (NT * 4);
            int co = rem >> 2, part = rem & 3;
            gb[r] = (tap * COUT + n0 + co) * 32 + part * 8;
            lb[r] = (tap * NT + co) * PAD + part * 8;
        }
    }

    f32x4 acc[4][NF];
#pragma unroll
    for (int mf = 0; mf < 4; ++mf)
#pragma unroll
        for (int nf = 0; nf < NF; ++nf)
            acc[mf][nf] = (f32x4){0.f, 0.f, 0.f, 0.f};

    uint4 ra[CA], rb[CB];

    auto loadA = [&](int cib) {
        const int blk = cib / SUB;
        const int inner = (cib - blk * SUB) * 32;
        const ushort_t* base = in + ((size_t)(b * NBI + blk) * (H * W)) * CSTR + inner;
#pragma unroll
        for (int r = 0; r < CA; ++r) {
            uint4 v = make_uint4(0, 0, 0, 0);
            if (ga[r] >= 0) {
                v = *(const uint4*)(base + ga[r]);
                if (GNIN) v = gn8(v, &sshare[cib * 32 + pr[r] * 8]);
            }
            ra[r] = v;
        }
    };
    auto loadB = [&](int cib) {
        const ushort_t* wb = wp + (size_t)cib * 9 * COUT * 32;
#pragma unroll
        for (int r = 0; r < CB; ++r)
            if (gb[r] >= 0) rb[r] = *(const uint4*)(wb + gb[r]);
    };

    loadA(0); loadB(0);

    for (int cib = 0; cib < NCB; ++cib) {
        __syncthreads();
#pragma unroll
        for (int r = 0; r < CA; ++r)
            if (tid + r * 256 < AITER) *(uint4*)&lA[la[r]] = ra[r];
#pragma unroll
        for (int r = 0; r < CB; ++r)
            if (tid + r * 256 < BITER) *(uint4*)&lB[lb[r]] = rb[r];
        __syncthreads();
        if (cib + 1 < NCB) { loadA(cib + 1); loadB(cib + 1); }

#pragma unroll
        for (int tap = 0; tap < 9; ++tap) {
            const int kh = tap / 3, kw = tap % 3;
            short8 af[4];
#pragma unroll
            for (int mf = 0; mf < 4; ++mf)
                af[mf] = *(const short8*)&lA[((wid + kh) * IW + mf * 16 + nl + kw) * PAD + ql];
            short8 bf[NF];
#pragma unroll
            for (int nf = 0; nf < NF; ++nf)
                bf[nf] = *(const short8*)&lB[(tap * NT + nf * 16 + nl) * PAD + ql];
#pragma unroll
            for (int mf = 0; mf < 4; ++mf)
#pragma unroll
                for (int nf = 0; nf < NF; ++nf)
                    acc[mf][nf] = __builtin_amdgcn_mfma_f32_16x16x32_bf16(
                        af[mf], bf[nf], acc[mf][nf], 0, 0, 0);
        }
    }

    float bs[NF];
#pragma unroll
    for (int nf = 0; nf < NF; ++nf) bs[nf] = bias[n0 + nf * 16 + nl];

    if (STATS) {
#pragma unroll
        for (int nf = 0; nf < NF; ++nf) {
            float s = 0.f, ss = 0.f;
#pragma unroll
            for (int mf = 0; mf < 4; ++mf)
#pragma unroll
                for (int rg = 0; rg < 4; ++rg) {
                    float v = acc[mf][nf][rg] + bs[nf];
                    s += v; ss += v * v;
                }
            red_stats(s, ss);
            if (quad == 0 && (nl & 7) == 0) sred[wid][nf * 2 + (nl >> 3)] = make_float2(s, ss);
        }
    }

    __syncthreads();
#pragma unroll
    for (int mf = 0; mf < 4; ++mf)
#pragma unroll
        for (int nf = 0; nf < NF; ++nf)
#pragma unroll
            for (int rg = 0; rg < 4; ++rg) {
                int px = wid * 64 + mf * 16 + quad * 4 + rg;
                lE[px * EP + nf * 16 + nl] = f2bf(acc[mf][nf][rg] + bs[nf]);
            }
    __syncthreads();
    // channel-blocked output: [B, NBO, H, W, NT] — fully contiguous per block
#pragma unroll
    for (int it = 0; it < NT / 8; ++it) {
        int idx = it * 256 + tid;
        int px = idx / (NT / 8), ck = idx % (NT / 8);
        int row = px >> 6, col = px & 63;
        uint4 v = *(const uint4*)&lE[px * EP + ck * 8];
        *(uint4*)(outp + ((((size_t)(b * NBO + nb) * H + h0 + row) * W + w0 + col) * NT + ck * 8)) = v;
    }
    if (STATS && tid < 2 * NF) {
        float2 t0 = sred[0][tid], t1 = sred[1][tid], t2 = sred[2][tid], t3 = sred[3][tid];
        pstats_out[((size_t)b * (COUT / 8) + (n0 >> 3) + tid) * NPBO + (ht * NW + wt)] =
            make_float2(t0.x + t1.x + t2.x + t3.x, t0.y + t1.y + t2.y + t3.y);
    }
}

// ---------------------------------------------------------------------------
// conv2 (3x3 stride-2) as dense parity conv (input GN1 fused), XCD-swizzled.
// in A1 [16,128,128,64] bf16 -> out A2 blocked [16,2,64,64,64] bf16
// ---------------------------------------------------------------------------
__global__ __launch_bounds__(256, 2) void conv2p_mfma(const ushort_t* __restrict__ in,
                                                      const ushort_t* __restrict__ wp,
                                                      const float* __restrict__ bias,
                                                      ushort_t* __restrict__ outp,
                                                      float2* __restrict__ pstats_out,
                                                      const float2* __restrict__ pstats_in,
                                                      const float* __restrict__ gamma,
                                                      const float* __restrict__ beta,
                                                      float invC) {
    constexpr int IW = 65, NRI = 5, NF = 4, NT = 64;
    constexpr int AITER = NRI * IW * 4;
    constexpr int CA = 6, CB = 4;
    constexpr int EP = NT + 8;
    __shared__ ushort_t smem[NRI * IW * PAD + 4 * NT * PAD];
    __shared__ float2 sred[4][8];
    __shared__ float2 sshare[64];
    ushort_t* lA = smem;
    ushort_t* lB = smem + NRI * IW * PAD;
    ushort_t* lE = smem;

    // grid 512 = 8 xcd * 2 half * 32 local(16 ht x 2 nb)
    int bid = blockIdx.x;
    int xcd = bid & 7;
    int rest = bid >> 3;
    int half = rest >> 5;
    int local = rest & 31;
    int b = xcd + 8 * half;
    int ht = local & 15;
    int nb = local >> 4;
    int h0 = ht * 4, n0 = nb * 64;
    int tid = threadIdx.x;
    int lane = tid & 63, wid = tid >> 6;
    int nl = lane & 15, quad = lane >> 4, ql = quad * 8;

    fill_ss<64, 64>(sshare, pstats_in, gamma, beta, b, invC, tid);
    __syncthreads();

    int r2[CA], c2[CA], la[CA], g4[CA], pr[CA];
#pragma unroll
    for (int r = 0; r < CA; ++r) {
        int i = tid + r * 256;
        r2[r] = -1000; c2[r] = 0; la[r] = 0; g4[r] = 0; pr[r] = 0;
        if (i < AITER) {
            int tr = i / (IW * 4); int rem = i - tr * (IW * 4);
            int p = rem >> 2, part = rem & 3;
            r2[r] = 2 * (h0 - 1 + tr);
            c2[r] = 2 * (p - 1);
            la[r] = (tr * IW + p) * PAD + part * 8;
            g4[r] = part * 8;
            pr[r] = part;
        }
    }
    int gb[CB], lb[CB];
#pragma unroll
    for (int r = 0; r < CB; ++r) {
        int i = tid + r * 256;
        int tap = i >> 8, co = (i >> 2) & 63, part = i & 3;
        gb[r] = (tap * 128 + n0 + co) * 32 + part * 8;
        lb[r] = (tap * NT + co) * PAD + part * 8;
    }

    f32x4 acc[4][NF];
#pragma unroll
    for (int mf = 0; mf < 4; ++mf)
#pragma unroll
        for (int nf = 0; nf < NF; ++nf)
            acc[mf][nf] = (f32x4){0.f, 0.f, 0.f, 0.f};

    const ushort_t* ibase = in + (size_t)b * 128 * 128 * 64;
    uint4 ra[CA], rb[CB];

    auto loadA = [&](int cib) {
        const int p = cib >> 2, q = (cib >> 1) & 1, ch32 = (cib & 1) * 32;
#pragma unroll
        for (int r = 0; r < CA; ++r) {
            int ih = r2[r] + p, iw = c2[r] + q;
            uint4 v = make_uint4(0, 0, 0, 0);
            if ((unsigned)ih < 128u && (unsigned)iw < 128u) {
                v = *(const uint4*)(ibase + ((ih << 7) + iw) * 64 + ch32 + g4[r]);
                v = gn8(v, &sshare[ch32 + pr[r] * 8]);
            }
            ra[r] = v;
        }
    };
    auto loadB = [&](int cib) {
        const ushort_t* wb = wp + (size_t)cib * 4 * 128 * 32;
#pragma unroll
        for (int r = 0; r < CB; ++r)
            rb[r] = *(const uint4*)(wb + gb[r]);
    };

    loadA(0); loadB(0);

#pragma unroll
    for (int cib = 0; cib < 8; ++cib) {
        const int p = cib >> 2, q = (cib >> 1) & 1;
        __syncthreads();
#pragma unroll
        for (int r = 0; r < CA; ++r)
            if (tid + r * 256 < AITER) *(uint4*)&lA[la[r]] = ra[r];
#pragma unroll
        for (int r = 0; r < CB; ++r) *(uint4*)&lB[lb[r]] = rb[r];
        __syncthreads();
        if (cib + 1 < 8) { loadA(cib + 1); loadB(cib + 1); }

#pragma unroll
        for (int kh = 0; kh < 2; ++kh)
#pragma unroll
            for (int kw = 0; kw < 2; ++kw)
                if ((kh == 1 || p == 1) && (kw == 1 || q == 1)) {
                    short8 af[4];
#pragma unroll
                    for (int mf = 0; mf < 4; ++mf)
                        af[mf] = *(const short8*)&lA[((wid + kh) * IW + mf * 16 + nl + kw) * PAD + ql];
                    short8 bf[NF];
#pragma unroll
                    for (int nf = 0; nf < NF; ++nf)
                        bf[nf] = *(const short8*)&lB[((kh * 2 + kw) * NT + nf * 16 + nl) * PAD + ql];
#pragma unroll
                    for (int mf = 0; mf < 4; ++mf)
#pragma unroll
                        for (int nf = 0; nf < NF; ++nf)
                            acc[mf][nf] = __builtin_amdgcn_mfma_f32_16x16x32_bf16(
                                af[mf], bf[nf], acc[mf][nf], 0, 0, 0);
                }
    }

    float bs[NF];
#pragma unroll
    for (int nf = 0; nf < NF; ++nf) bs[nf] = bias[n0 + nf * 16 + nl];
#pragma unroll
    for (int nf = 0; nf < NF; ++nf) {
        float s = 0.f, ss = 0.f;
#pragma unroll
        for (int mf = 0; mf < 4; ++mf)
#pragma unroll
            for (int rg = 0; rg < 4; ++rg) {
                float v = acc[mf][nf][rg] + bs[nf];
                s += v; ss += v * v;
            }
        red_stats(s, ss);
        if (quad == 0 && (nl & 7) == 0) sred[wid][nf * 2 + (nl >> 3)] = make_float2(s, ss);
    }

    __syncthreads();
#pragma unroll
    for (int mf = 0; mf < 4; ++mf)
#pragma unroll
        for (int nf = 0; nf < NF; ++nf)
#pragma unroll
            for (int rg = 0; rg < 4; ++rg) {
                int px = wid * 64 + mf * 16 + quad * 4 + rg;
                lE[px * EP + nf * 16 + nl] = f2bf(acc[mf][nf][rg] + bs[nf]);
            }
    __syncthreads();
    // blocked output [16, 2, 64, 64, 64]
#pragma unroll
    for (int it = 0; it < 8; ++it) {
        int idx = it * 256 + tid;
        int px = idx >> 3, ck = idx & 7;
        int row = px >> 6, col = px & 63;
        uint4 v = *(const uint4*)&lE[px * EP + ck * 8];
        *(uint4*)(outp + ((((size_t)(b * 2 + nb) * 64 + h0 + row) * 64 + col) * 64 + ck * 8)) = v;
    }
    if (tid < 8) {
        float2 t0 = sred[0][tid], t1 = sred[1][tid], t2 = sred[2][tid], t3 = sred[3][tid];
        pstats_out[((size_t)b * 16 + (n0 >> 3) + tid) * 16 + ht] =
            make_float2(t0.x + t1.x + t2.x + t3.x, t0.y + t1.y + t2.y + t3.y);
    }
}

// ---------------------------------------------------------------------------
// ConvTranspose 4x4 s2 p1 (input GN4 fused), 4 output-parity phases, XCD-swizzled.
// in A4 blocked [16,2,64,64,64] -> out A5 [16,128,128,64]
// ---------------------------------------------------------------------------
__global__ __launch_bounds__(256, 2) void convt_mfma(const ushort_t* __restrict__ in,
                                                     const ushort_t* __restrict__ wp,
                                                     const float* __restrict__ bias,
                                                     ushort_t* __restrict__ outp,
                                                     float2* __restrict__ pstats_out,
                                                     const float2* __restrict__ pstats_in,
                                                     const float* __restrict__ gamma,
                                                     const float* __restrict__ beta,
                                                     float invC) {
    constexpr int CIN = 128, COUT = 64, NT = 64, NF = 4;
    constexpr int IW = 66, NRI = 5;
    constexpr int AITER = NRI * IW * 4;
    constexpr int CA = 6, CB = 4;
    constexpr int EP = NT + 8;
    __shared__ ushort_t smem[NRI * IW * PAD + 4 * NT * PAD];
    __shared__ float2 sred[4][8];
    __shared__ float2 sshare[CIN];
    ushort_t* lA = smem;
    ushort_t* lB = smem + NRI * IW * PAD;
    ushort_t* lE = smem;

    // grid 1024 = 8 xcd * 2 half * 64 local(16 ht x 4 ph)
    int bid = blockIdx.x;
    int xcd = bid & 7;
    int rest = bid >> 3;
    int half = rest >> 6;
    int local = rest & 63;
    int b = xcd + 8 * half;
    int ht = local & 15;
    int ph = local >> 4;
    int eh = ph >> 1, ew = ph & 1;
    int ho0 = ht * 4;
    int tid = threadIdx.x;
    int lane = tid & 63, wid = tid >> 6;
    int nl = lane & 15, quad = lane >> 4, ql = quad * 8;

    fill_ss<CIN, 16>(sshare, pstats_in, gamma, beta, b, invC, tid);
    __syncthreads();

    int ga[CA], la[CA], pr[CA];
#pragma unroll
    for (int r = 0; r < CA; ++r) {
        int i = tid + r * 256;
        ga[r] = -1; la[r] = 0; pr[r] = 0;
        if (i < AITER) {
            int tr = i / (IW * 4); int rem = i - tr * (IW * 4);
            int p = rem >> 2, part = rem & 3;
            la[r] = (tr * IW + p) * PAD + part * 8;
            pr[r] = part;
            int ih = ho0 + tr - (1 - eh), iw = p - 1;
            if ((unsigned)ih < 64u && (unsigned)iw < 64u)
                ga[r] = (ih * 64 + iw) * 64 + part * 8;
        }
    }
    int gb[CB], lb[CB];
#pragma unroll
    for (int r = 0; r < CB; ++r) {
        int i = tid + r * 256;
        int tap = i >> 8, co = (i >> 2) & 63, part = i & 3;
        gb[r] = (tap * COUT + co) * 32 + part * 8;
        lb[r] = (tap * NT + co) * PAD + part * 8;
    }

    f32x4 acc[4][NF];
#pragma unroll
    for (int mf = 0; mf < 4; ++mf)
#pragma unroll
        for (int nf = 0; nf < NF; ++nf)
            acc[mf][nf] = (f32x4){0.f, 0.f, 0.f, 0.f};

    uint4 ra[CA], rb[CB];

    auto loadA = [&](int cib) {
        const int blk = cib >> 1;
        const int inner = (cib & 1) * 32;
        const ushort_t* base = in + ((size_t)(b * 2 + blk) * 4096) * 64 + inner;
#pragma unroll
        for (int r = 0; r < CA; ++r) {
            uint4 v = make_uint4(0, 0, 0, 0);
            if (ga[r] >= 0) {
                v = *(const uint4*)(base + ga[r]);
                v = gn8(v, &sshare[cib * 32 + pr[r] * 8]);
            }
            ra[r] = v;
        }
    };
    auto loadB = [&](int cib) {
        const ushort_t* wb = wp + ((size_t)ph * 4 + cib) * 4 * COUT * 32;
#pragma unroll
        for (int r = 0; r < CB; ++r)
            rb[r] = *(const uint4*)(wb + gb[r]);
    };

    loadA(0); loadB(0);

    for (int cib = 0; cib < 4; ++cib) {
        __syncthreads();
#pragma unroll
        for (int r = 0; r < CA; ++r)
            if (tid + r * 256 < AITER) *(uint4*)&lA[la[r]] = ra[r];
#pragma unroll
        for (int r = 0; r < CB; ++r) *(uint4*)&lB[lb[r]] = rb[r];
        __syncthreads();
        if (cib + 1 < 4) { loadA(cib + 1); loadB(cib + 1); }

#pragma unroll
        for (int tap = 0; tap < 4; ++tap) {
            const int rs = tap >> 1, cs = tap & 1;
            short8 af[4];
#pragma unroll
            for (int mf = 0; mf < 4; ++mf)
                af[mf] = *(const short8*)&lA[((wid + rs) * IW + mf * 16 + nl + cs + ew) * PAD + ql];
            short8 bf[NF];
#pragma unroll
            for (int nf = 0; nf < NF; ++nf)
                bf[nf] = *(const short8*)&lB[(tap * NT + nf * 16 + nl) * PAD + ql];
#pragma unroll
            for (int mf = 0; mf < 4; ++mf)
#pragma unroll
                for (int nf = 0; nf < NF; ++nf)
                    acc[mf][nf] = __builtin_amdgcn_mfma_f32_16x16x32_bf16(
                        af[mf], bf[nf], acc[mf][nf], 0, 0, 0);
        }
    }

    float bs[NF];
#pragma unroll
    for (int nf = 0; nf < NF; ++nf) bs[nf] = bias[nf * 16 + nl];
#pragma unroll
    for (int nf = 0; nf < NF; ++nf) {
        float s = 0.f, ss = 0.f;
#pragma unroll
        for (int mf = 0; mf < 4; ++mf)
#pragma unroll
            for (int rg = 0; rg < 4; ++rg) {
                float v = acc[mf][nf][rg] + bs[nf];
                s += v; ss += v * v;
            }
        red_stats(s, ss);
        if (quad == 0 && (nl & 7) == 0) sred[wid][nf * 2 + (nl >> 3)] = make_float2(s, ss);
    }

    __syncthreads();
#pragma unroll
    for (int mf = 0; mf < 4; ++mf)
#pragma unroll
        for (int nf = 0; nf < NF; ++nf)
#pragma unroll
            for (int rg = 0; rg < 4; ++rg) {
                int px = wid * 64 + mf * 16 + quad * 4 + rg;
                lE[px * EP + nf * 16 + nl] = f2bf(acc[mf][nf][rg] + bs[nf]);
            }
    __syncthreads();
#pragma unroll
    for (int it = 0; it < 8; ++it) {
        int idx = it * 256 + tid;
        int px = idx >> 3, ck = idx & 7;
        int row = px >> 6, wo = px & 63;
        int oh = 2 * (ho0 + row) + eh;
        uint4 v = *(const uint4*)&lE[px * EP + ck * 8];
        *(uint4*)(outp + (((size_t)b * 128 + oh) * 128 + 2 * wo + ew) * 64 + ck * 8) = v;
    }
    if (tid < 8) {
        float2 t0 = sred[0][tid], t1 = sred[1][tid], t2 = sred[2][tid], t3 = sred[3][tid];
        pstats_out[((size_t)b * 8 + tid) * 64 + (ht * 4 + ph)] =
            make_float2(t0.x + t1.x + t2.x + t3.x, t0.y + t1.y + t2.y + t3.y);
    }
}

// ---------------------------------------------------------------------------
extern "C" void kernel_launch(void* const* d_in, const int* in_sizes, int n_in,
                              void* d_out, int out_size, void* d_ws, size_t ws_size,
                              hipStream_t stream) {
    const float* x   = (const float*)d_in[0];
    const float* Kd  = (const float*)d_in[1];
    const float* Kr  = (const float*)d_in[2];
    const float* W1  = (const float*)d_in[3];  const float* b1  = (const float*)d_in[4];
    const float* g1  = (const float*)d_in[5];  const float* be1 = (const float*)d_in[6];
    const float* W2  = (const float*)d_in[7];  const float* b2  = (const float*)d_in[8];
    const float* g2  = (const float*)d_in[9];  const float* be2 = (const float*)d_in[10];
    const float* W3  = (const float*)d_in[11]; const float* b3  = (const float*)d_in[12];
    const float* g3  = (const float*)d_in[13]; const float* be3 = (const float*)d_in[14];
    const float* W4  = (const float*)d_in[15]; const float* b4  = (const float*)d_in[16];
    const float* g4  = (const float*)d_in[17]; const float* be4 = (const float*)d_in[18];
    const float* Wt  = (const float*)d_in[19]; const float* bt  = (const float*)d_in[20];
    const float* g5  = (const float*)d_in[21]; const float* be5 = (const float*)d_in[22];
    const float* W6  = (const float*)d_in[23]; const float* b6  = (const float*)d_in[24];

    ushort_t* U  = (ushort_t*)d_ws;
    ushort_t* V  = U + 8388608;
    ushort_t* WP = V + 16777216;
    ushort_t* wp1 = WP;
    ushort_t* wp2 = WP + 18432;
    ushort_t* wp3 = WP + 149504;
    ushort_t* wp4 = WP + 444416;
    ushort_t* wpt = WP + 739328;
    ushort_t* wp6 = WP + 870400;
    // per-block partial GN stats (fully rewritten each launch; no init needed)
    float2* PS = (float2*)(WP + 879616);
    float2* P1 = PS;           // conv1: 16*8*64  = 8192
    float2* P2 = PS + 8192;    // conv2: 16*16*16 = 4096
    float2* P3 = PS + 12288;   // conv3: 16*32*16 = 8192
    float2* P4 = PS + 20480;   // conv4: 16*16*16 = 4096
    float2* P5 = PS + 24576;   // convT: 16*8*64  = 8192
    float* out = (float*)d_out;

    pack_all<<<3436, 256, 0, stream>>>(W1, W2, W3, W4, Wt, W6, WP);

    // DWT: x -> U (A0 [16,128,128,32])
    dwt_nhwc<<<1024, 256, 0, stream>>>(x, Kd, U);

    // conv1 32->64 @128x128: U -> V (A1 [16,128,128,64]), partials P1
    conv_mfma<32, 64, 128, 128, true, false, 16>
        <<<1024, 256, 0, stream>>>(U, wp1, b1, V, P1, nullptr, nullptr, nullptr, 0.f);

    // conv2 (parity, GN1 in) 64->128 s2: V -> U (A2 [16,2,64,64,64]), partials P2
    conv2p_mfma<<<512, 256, 0, stream>>>(V, wp2, b2, U, P2,
                                         P1, g1, be1, 1.f / 131072.f);

    // conv3 (GN2 in) 128->256 @64x64: U -> V (A3 [16,4,64,64,64]), partials P3
    conv_mfma<128, 256, 64, 64, true, true, 16>
        <<<1024, 256, 0, stream>>>(U, wp3, b3, V, P3,
                                   P2, g2, be2, 1.f / 32768.f);

    // conv4 (GN3 in) 256->128 @64x64: V -> U (A4 [16,2,64,64,64]), partials P4
    conv_mfma<256, 128, 64, 64, true, true, 16>
        <<<512, 256, 0, stream>>>(V, wp4, b4, U, P4,
                                  P3, g3, be3, 1.f / 32768.f);

    // convT (GN4 in) 128->64 x2: U -> V (A5 [16,128,128,64]), partials P5
    convt_mfma<<<1024, 256, 0, stream>>>(U, wpt, bt, V, P5,
                                         P4, g4, be4, 1.f / 32768.f);

    // conv6 (GN5 in) 64->16 @128x128: V -> U (A6 [16,128,128,16])
    conv_mfma<64, 16, 128, 128, false, true, 64>
        <<<1024, 256, 0, stream>>>(V, wp6, b6, U, nullptr,
                                   P5, g5, be5, 1.f / 131072.f);

    // IDWT: U -> out
    idwt_nhwc<<<1024, 256, 0, stream>>>(U, Kr, out);
}

// Round 8
// 367.965 us; speedup vs baseline: 1.2180x; 1.2180x over previous
//
#include <hip/hip_runtime.h>

typedef unsigned short ushort_t;
typedef unsigned int uint_t;
typedef __attribute__((ext_vector_type(8))) short short8;
typedef __attribute__((ext_vector_type(4))) float f32x4;

#define PAD 40   // staging LDS elems per pixel row: bank stride 20 -> 2-way (free)

__device__ __forceinline__ ushort_t f2bf(float f) {
    uint_t u = __float_as_uint(f);
    u = (u + 0x7FFFu + ((u >> 16) & 1u)) >> 16;
    return (ushort_t)u;
}
__device__ __forceinline__ float bf2f(ushort_t h) {
    return __uint_as_float(((uint_t)h) << 16);
}

__device__ __forceinline__ void red_stats(float& s, float& ss) {
    s += __shfl_xor(s, 16); ss += __shfl_xor(ss, 16);
    s += __shfl_xor(s, 32); ss += __shfl_xor(ss, 32);
    s += __shfl_xor(s, 1);  ss += __shfl_xor(ss, 1);
    s += __shfl_xor(s, 2);  ss += __shfl_xor(ss, 2);
    s += __shfl_xor(s, 4);  ss += __shfl_xor(ss, 4);
}

__device__ __forceinline__ uint4 gn8(uint4 v, const float2* ss) {
    uint_t u[4] = {v.x, v.y, v.z, v.w};
    uint_t r[4];
#pragma unroll
    for (int p = 0; p < 4; ++p) {
        float2 s0 = ss[2 * p], s1 = ss[2 * p + 1];
        float f0 = fmaxf(bf2f((ushort_t)(u[p] & 0xffffu)) * s0.x + s0.y, 0.f);
        float f1 = fmaxf(bf2f((ushort_t)(u[p] >> 16)) * s1.x + s1.y, 0.f);
        r[p] = (uint_t)f2bf(f0) | ((uint_t)f2bf(f1) << 16);
    }
    return make_uint4(r[0], r[1], r[2], r[3]);
}

template<int C, int NPB>
__device__ __forceinline__ void fill_ss(float2* sshare, const float2* __restrict__ pin,
                                        const float* __restrict__ gamma,
                                        const float* __restrict__ beta,
                                        int b, float invC, int tid) {
    for (int c = tid; c < C; c += 256) {
        const float2* p = pin + ((size_t)b * (C / 8) + (c >> 3)) * NPB;
        float s = 0.f, ss = 0.f;
#pragma unroll 8
        for (int i = 0; i < NPB; ++i) { s += p[i].x; ss += p[i].y; }
        float mean = s * invC;
        float rstd = rsqrtf(ss * invC - mean * mean + 1e-5f);
        float sc = gamma[c] * rstd;
        sshare[c] = make_float2(sc, beta[c] - mean * sc);
    }
}

// ---------------------------------------------------------------------------
// Weight packing (one merged kernel)
// ---------------------------------------------------------------------------
template<int CIN, int COUT>
__device__ __forceinline__ void pack3(const float* __restrict__ W, ushort_t* __restrict__ wp, int idx) {
    int kk = idx & 31;
    int t = idx >> 5;
    int co = t % COUT; t /= COUT;
    int tap = t % 9;
    int cib = t / 9;
    wp[idx] = f2bf(W[(co * CIN + cib * 32 + kk) * 9 + tap]);
}

__device__ __forceinline__ void pack2p(const float* __restrict__ W2, ushort_t* __restrict__ wp, int idx) {
    int kk = idx & 31;
    int co = (idx >> 5) & 127;
    int tap = (idx >> 12) & 3;
    int cib = idx >> 14;
    int p = cib >> 2, q = (cib >> 1) & 1, chalf = cib & 1;
    int kh = 2 * (tap >> 1) + p - 1;
    int kw = 2 * (tap & 1) + q - 1;
    float v = 0.f;
    if (kh >= 0 && kh < 3 && kw >= 0 && kw < 3)
        v = W2[(co * 64 + chalf * 32 + kk) * 9 + kh * 3 + kw];
    wp[idx] = f2bf(v);
}

__device__ __forceinline__ void packt(const float* __restrict__ Wt, ushort_t* __restrict__ wp, int idx) {
    int kk = idx & 31;
    int t = idx >> 5;
    int co = t & 63; t >>= 6;
    int tap = t & 3; t >>= 2;
    int cib = t & 3;
    int ph = t >> 2;
    int rs = tap >> 1, cs = tap & 1;
    int eh = ph >> 1, ew = ph & 1;
    int kh = eh ? (rs ? 0 : 2) : (rs ? 1 : 3);
    int kw = ew ? (cs ? 0 : 2) : (cs ? 1 : 3);
    wp[idx] = f2bf(Wt[((cib * 32 + kk) * 64 + co) * 16 + kh * 4 + kw]);
}

__global__ __launch_bounds__(256) void pack_all(const float* __restrict__ W1,
                                                const float* __restrict__ W2,
                                                const float* __restrict__ W3,
                                                const float* __restrict__ W4,
                                                const float* __restrict__ Wt,
                                                const float* __restrict__ W6,
                                                ushort_t* __restrict__ WP) {
    int idx = blockIdx.x * 256 + threadIdx.x;
    if (idx < 18432)        pack3<32, 64>(W1, WP, idx);
    else if (idx < 149504)  pack2p(W2, WP + 18432, idx - 18432);
    else if (idx < 444416)  pack3<128, 256>(W3, WP + 149504, idx - 149504);
    else if (idx < 739328)  pack3<256, 128>(W4, WP + 444416, idx - 444416);
    else if (idx < 870400)  packt(Wt, WP + 739328, idx - 739328);
    else if (idx < 879616)  pack3<64, 16>(W6, WP + 870400, idx - 870400);
}

// ---------------------------------------------------------------------------
// DWT: x NCHW fp32 [16,8,256,256] -> NHWC bf16 [16,128,128,32]
// ---------------------------------------------------------------------------
__global__ __launch_bounds__(256) void dwt_nhwc(const float* __restrict__ x,
                                                const float* __restrict__ Kd,
                                                ushort_t* __restrict__ out) {
    int idx = blockIdx.x * 256 + threadIdx.x;
    int w = idx & 127, h = (idx >> 7) & 127, b = idx >> 14;
    float k[16];
#pragma unroll
    for (int i = 0; i < 16; ++i) k[i] = Kd[i];
    const float* xb = x + (size_t)b * 8 * 65536;
    uint_t uu[16];
#pragma unroll
    for (int ci = 0; ci < 8; ++ci) {
        const float* p = xb + ci * 65536 + (2 * h) * 256 + 2 * w;
        float2 r0 = *(const float2*)p;
        float2 r1 = *(const float2*)(p + 256);
        ushort_t o[4];
#pragma unroll
        for (int sb = 0; sb < 4; ++sb) {
            float v = r0.x * k[sb*4] + r0.y * k[sb*4+1] + r1.x * k[sb*4+2] + r1.y * k[sb*4+3];
            o[sb] = f2bf(v);
        }
        uu[ci*2]   = (uint_t)o[0] | ((uint_t)o[1] << 16);
        uu[ci*2+1] = (uint_t)o[2] | ((uint_t)o[3] << 16);
    }
    uint4* dst = (uint4*)(out + (size_t)idx * 32);
    dst[0] = make_uint4(uu[0], uu[1], uu[2], uu[3]);
    dst[1] = make_uint4(uu[4], uu[5], uu[6], uu[7]);
    dst[2] = make_uint4(uu[8], uu[9], uu[10], uu[11]);
    dst[3] = make_uint4(uu[12], uu[13], uu[14], uu[15]);
}

// ---------------------------------------------------------------------------
// IDWT: in NHWC bf16 [16,128,128,16] -> out NCHW fp32 [16,4,256,256]
// ---------------------------------------------------------------------------
__global__ __launch_bounds__(256) void idwt_nhwc(const ushort_t* __restrict__ cin,
                                                 const float* __restrict__ Kr,
                                                 float* __restrict__ out) {
    int idx = blockIdx.x * 256 + threadIdx.x;
    int w = idx & 127, h = (idx >> 7) & 127, b = idx >> 14;
    float k[16];
#pragma unroll
    for (int i = 0; i < 16; ++i) k[i] = Kr[i];
    const uint4* pv = (const uint4*)(cin + (size_t)idx * 16);
    uint4 v0 = pv[0], v1 = pv[1];
    uint_t uw[8] = {v0.x, v0.y, v0.z, v0.w, v1.x, v1.y, v1.z, v1.w};
    float cs[16];
#pragma unroll
    for (int i = 0; i < 8; ++i) {
        cs[2*i]   = bf2f((ushort_t)(uw[i] & 0xffffu));
        cs[2*i+1] = bf2f((ushort_t)(uw[i] >> 16));
    }
#pragma unroll
    for (int c = 0; c < 4; ++c) {
        float y00 = 0, y01 = 0, y10 = 0, y11 = 0;
#pragma unroll
        for (int sb = 0; sb < 4; ++sb) {
            float v = cs[c * 4 + sb];
            y00 += v * k[sb*4];   y01 += v * k[sb*4+1];
            y10 += v * k[sb*4+2]; y11 += v * k[sb*4+3];
        }
        float* ob = out + ((size_t)(b * 4 + c) * 256 + 2 * h) * 256 + 2 * w;
        *(float2*)ob = make_float2(y00, y01);
        *(float2*)(ob + 256) = make_float2(y10, y11);
    }
}

// ---------------------------------------------------------------------------
// Implicit-GEMM 3x3 stride-1 conv, MFMA 16x16x32, XCD-swizzled grid.
// A staged in LDS; B (weights) read directly from global (L2-resident) with
// one-tap register prefetch. LDS ~37KB -> 4 blocks/CU.
// ---------------------------------------------------------------------------
template<int CIN, int COUT, int H, int W, bool STATS, bool GNIN, int NPBI>
__global__ __launch_bounds__(256, 2) void conv_mfma(const ushort_t* __restrict__ in,
                                                    const ushort_t* __restrict__ wp,
                                                    const float* __restrict__ bias,
                                                    ushort_t* __restrict__ outp,
                                                    float2* __restrict__ pstats_out,
                                                    const float2* __restrict__ pstats_in,
                                                    const float* __restrict__ gamma,
                                                    const float* __restrict__ beta,
                                                    float invC) {
    constexpr int NT = (COUT < 64) ? COUT : 64;
    constexpr int NF = NT / 16;
    constexpr int NCB = CIN / 32;
    constexpr int CSTR = (CIN < 64) ? CIN : 64;
    constexpr int NBI = CIN / CSTR;
    constexpr int SUB = CSTR / 32;
    constexpr int NBO = COUT / NT;
    constexpr int IW = 66, NRI = 6;
    constexpr int AITER = NRI * IW * 4;
    constexpr int CA = (AITER + 255) / 256;
    constexpr int NW = W / 64, NH = H / 4;
    constexpr int PB = NBO * NW * NH;
    constexpr int NPBO = NH * NW;
    constexpr int EP = NT + 8;
    constexpr int ASZ = NRI * IW * PAD;
    constexpr int SMEM = (ASZ > 256 * EP) ? ASZ : 256 * EP;

    __shared__ ushort_t smem[SMEM];
    __shared__ float2 sred[4][8];
    __shared__ float2 sshare[CIN];
    ushort_t* lA = smem;
    ushort_t* lE = smem;

    int bid = blockIdx.x;
    int xcd = bid & 7;
    int rest = bid >> 3;
    int half = rest / PB;
    int local = rest - half * PB;
    int b = xcd + 8 * half;
    int ht = local % NH; local /= NH;
    int wt = local % NW; local /= NW;
    int nb = local;
    int h0 = ht * 4, w0 = wt * 64, n0 = nb * NT;
    int tid = threadIdx.x;
    int lane = tid & 63, wid = tid >> 6;
    int nl = lane & 15, quad = lane >> 4, ql = quad * 8;

    if (GNIN) {
        fill_ss<CIN, NPBI>(sshare, pstats_in, gamma, beta, b, invC, tid);
        __syncthreads();
    }

    int ga[CA], la[CA], pr[CA];
#pragma unroll
    for (int r = 0; r < CA; ++r) {
        int i = tid + r * 256;
        ga[r] = -1; la[r] = 0; pr[r] = 0;
        if (i < AITER) {
            int tr = i / (IW * 4); int rem = i - tr * (IW * 4);
            int p = rem >> 2, part = rem & 3;
            la[r] = (tr * IW + p) * PAD + part * 8;
            pr[r] = part;
            int ih = h0 - 1 + tr, iw = w0 - 1 + p;
            if ((unsigned)ih < (unsigned)H && (unsigned)iw < (unsigned)W)
                ga[r] = (ih * W + iw) * CSTR + part * 8;
        }
    }

    f32x4 acc[4][NF];
#pragma unroll
    for (int mf = 0; mf < 4; ++mf)
#pragma unroll
        for (int nf = 0; nf < NF; ++nf)
            acc[mf][nf] = (f32x4){0.f, 0.f, 0.f, 0.f};

    uint4 ra[CA];

    auto loadA = [&](int cib) {
        const int blk = cib / SUB;
        const int inner = (cib - blk * SUB) * 32;
        const ushort_t* base = in + ((size_t)(b * NBI + blk) * (H * W)) * CSTR + inner;
#pragma unroll
        for (int r = 0; r < CA; ++r) {
            uint4 v = make_uint4(0, 0, 0, 0);
            if (ga[r] >= 0) {
                v = *(const uint4*)(base + ga[r]);
                if (GNIN) v = gn8(v, &sshare[cib * 32 + pr[r] * 8]);
            }
            ra[r] = v;
        }
    };

    loadA(0);

    // per-lane weight base: co = n0 + nf*16 + nl, k-chunk = ql
    const ushort_t* wlane = wp + ((size_t)(n0 + nl)) * 32 + ql;

    for (int cib = 0; cib < NCB; ++cib) {
        __syncthreads();
#pragma unroll
        for (int r = 0; r < CA; ++r)
            if (tid + r * 256 < AITER) *(uint4*)&lA[la[r]] = ra[r];
        __syncthreads();
        if (cib + 1 < NCB) loadA(cib + 1);   // in flight during MFMA

        const ushort_t* wc = wlane + (size_t)cib * 9 * COUT * 32;
        short8 bfc[NF], bfn[NF];
#pragma unroll
        for (int nf = 0; nf < NF; ++nf)
            bfc[nf] = *(const short8*)(wc + nf * 512);

#pragma unroll
        for (int tap = 0; tap < 9; ++tap) {
            const int kh = tap / 3, kw = tap % 3;
            if (tap < 8) {
#pragma unroll
                for (int nf = 0; nf < NF; ++nf)
                    bfn[nf] = *(const short8*)(wc + (size_t)(tap + 1) * COUT * 32 + nf * 512);
            }
            short8 af[4];
#pragma unroll
            for (int mf = 0; mf < 4; ++mf)
                af[mf] = *(const short8*)&lA[((wid + kh) * IW + mf * 16 + nl + kw) * PAD + ql];
#pragma unroll
            for (int mf = 0; mf < 4; ++mf)
#pragma unroll
                for (int nf = 0; nf < NF; ++nf)
                    acc[mf][nf] = __builtin_amdgcn_mfma_f32_16x16x32_bf16(
                        af[mf], bfc[nf], acc[mf][nf], 0, 0, 0);
#pragma unroll
            for (int nf = 0; nf < NF; ++nf) bfc[nf] = bfn[nf];
        }
    }

    float bs[NF];
#pragma unroll
    for (int nf = 0; nf < NF; ++nf) bs[nf] = bias[n0 + nf * 16 + nl];

    if (STATS) {
#pragma unroll
        for (int nf = 0; nf < NF; ++nf) {
            float s = 0.f, ss = 0.f;
#pragma unroll
            for (int mf = 0; mf < 4; ++mf)
#pragma unroll
                for (int rg = 0; rg < 4; ++rg) {
                    float v = acc[mf][nf][rg] + bs[nf];
                    s += v; ss += v * v;
                }
            red_stats(s, ss);
            if (quad == 0 && (nl & 7) == 0) sred[wid][nf * 2 + (nl >> 3)] = make_float2(s, ss);
        }
    }

    __syncthreads();
#pragma unroll
    for (int mf = 0; mf < 4; ++mf)
#pragma unroll
        for (int nf = 0; nf < NF; ++nf)
#pragma unroll
            for (int rg = 0; rg < 4; ++rg) {
                int px = wid * 64 + mf * 16 + quad * 4 + rg;
                lE[px * EP + nf * 16 + nl] = f2bf(acc[mf][nf][rg] + bs[nf]);
            }
    __syncthreads();
#pragma unroll
    for (int it = 0; it < NT / 8; ++it) {
        int idx = it * 256 + tid;
        int px = idx / (NT / 8), ck = idx % (NT / 8);
        int row = px >> 6, col = px & 63;
        uint4 v = *(const uint4*)&lE[px * EP + ck * 8];
        *(uint4*)(outp + ((((size_t)(b * NBO + nb) * H + h0 + row) * W + w0 + col) * NT + ck * 8)) = v;
    }
    if (STATS && tid < 2 * NF) {
        float2 t0 = sred[0][tid], t1 = sred[1][tid], t2 = sred[2][tid], t3 = sred[3][tid];
        pstats_out[((size_t)b * (COUT / 8) + (n0 >> 3) + tid) * NPBO + (ht * NW + wt)] =
            make_float2(t0.x + t1.x + t2.x + t3.x, t0.y + t1.y + t2.y + t3.y);
    }
}

// ---------------------------------------------------------------------------
// conv2 (3x3 stride-2) as dense parity conv (input GN1 fused), XCD-swizzled.
// in A1 [16,128,128,64] bf16 -> out A2 blocked [16,2,64,64,64] bf16
// ---------------------------------------------------------------------------
__global__ __launch_bounds__(256, 2) void conv2p_mfma(const ushort_t* __restrict__ in,
                                                      const ushort_t* __restrict__ wp,
                                                      const float* __restrict__ bias,
                                                      ushort_t* __restrict__ outp,
                                                      float2* __restrict__ pstats_out,
                                                      const float2* __restrict__ pstats_in,
                                                      const float* __restrict__ gamma,
                                                      const float* __restrict__ beta,
                                                      float invC) {
    constexpr int IW = 65, NRI = 5, NF = 4, NT = 64;
    constexpr int AITER = NRI * IW * 4;
    constexpr int CA = 6;
    constexpr int EP = NT + 8;
    constexpr int ASZ = NRI * IW * PAD;
    constexpr int SMEM = (ASZ > 256 * EP) ? ASZ : 256 * EP;
    __shared__ ushort_t smem[SMEM];
    __shared__ float2 sred[4][8];
    __shared__ float2 sshare[64];
    ushort_t* lA = smem;
    ushort_t* lE = smem;

    int bid = blockIdx.x;
    int xcd = bid & 7;
    int rest = bid >> 3;
    int half = rest >> 5;
    int local = rest & 31;
    int b = xcd + 8 * half;
    int ht = local & 15;
    int nb = local >> 4;
    int h0 = ht * 4, n0 = nb * 64;
    int tid = threadIdx.x;
    int lane = tid & 63, wid = tid >> 6;
    int nl = lane & 15, quad = lane >> 4, ql = quad * 8;

    fill_ss<64, 64>(sshare, pstats_in, gamma, beta, b, invC, tid);
    __syncthreads();

    int r2[CA], c2[CA], la[CA], g4[CA], pr[CA];
#pragma unroll
    for (int r = 0; r < CA; ++r) {
        int i = tid + r * 256;
        r2[r] = -1000; c2[r] = 0; la[r] = 0; g4[r] = 0; pr[r] = 0;
        if (i < AITER) {
            int tr = i / (IW * 4); int rem = i - tr * (IW * 4);
            int p = rem >> 2, part = rem & 3;
            r2[r] = 2 * (h0 - 1 + tr);
            c2[r] = 2 * (p - 1);
            la[r] = (tr * IW + p) * PAD + part * 8;
            g4[r] = part * 8;
            pr[r] = part;
        }
    }

    f32x4 acc[4][NF];
#pragma unroll
    for (int mf = 0; mf < 4; ++mf)
#pragma unroll
        for (int nf = 0; nf < NF; ++nf)
            acc[mf][nf] = (f32x4){0.f, 0.f, 0.f, 0.f};

    const ushort_t* ibase = in + (size_t)b * 128 * 128 * 64;
    uint4 ra[CA];

    auto loadA = [&](int cib) {
        const int p = cib >> 2, q = (cib >> 1) & 1, ch32 = (cib & 1) * 32;
#pragma unroll
        for (int r = 0; r < CA; ++r) {
            int ih = r2[r] + p, iw = c2[r] + q;
            uint4 v = make_uint4(0, 0, 0, 0);
            if ((unsigned)ih < 128u && (unsigned)iw < 128u) {
                v = *(const uint4*)(ibase + ((ih << 7) + iw) * 64 + ch32 + g4[r]);
                v = gn8(v, &sshare[ch32 + pr[r] * 8]);
            }
            ra[r] = v;
        }
    };

    loadA(0);
    const ushort_t* wlane = wp + ((size_t)(n0 + nl)) * 32 + ql;

#pragma unroll
    for (int cib = 0; cib < 8; ++cib) {
        const int p = cib >> 2, q = (cib >> 1) & 1;
        __syncthreads();
#pragma unroll
        for (int r = 0; r < CA; ++r)
            if (tid + r * 256 < AITER) *(uint4*)&lA[la[r]] = ra[r];
        __syncthreads();
        if (cib + 1 < 8) loadA(cib + 1);

        const ushort_t* wc = wlane + (size_t)cib * 4 * 128 * 32;
#pragma unroll
        for (int kh = 0; kh < 2; ++kh)
#pragma unroll
            for (int kw = 0; kw < 2; ++kw)
                if ((kh == 1 || p == 1) && (kw == 1 || q == 1)) {
                    const int tap = kh * 2 + kw;
                    short8 bf[NF];
#pragma unroll
                    for (int nf = 0; nf < NF; ++nf)
                        bf[nf] = *(const short8*)(wc + (size_t)tap * 128 * 32 + nf * 512);
                    short8 af[4];
#pragma unroll
                    for (int mf = 0; mf < 4; ++mf)
                        af[mf] = *(const short8*)&lA[((wid + kh) * IW + mf * 16 + nl + kw) * PAD + ql];
#pragma unroll
                    for (int mf = 0; mf < 4; ++mf)
#pragma unroll
                        for (int nf = 0; nf < NF; ++nf)
                            acc[mf][nf] = __builtin_amdgcn_mfma_f32_16x16x32_bf16(
                                af[mf], bf[nf], acc[mf][nf], 0, 0, 0);
                }
    }

    float bs[NF];
#pragma unroll
    for (int nf = 0; nf < NF; ++nf) bs[nf] = bias[n0 + nf * 16 + nl];
#pragma unroll
    for (int nf = 0; nf < NF; ++nf) {
        float s = 0.f, ss = 0.f;
#pragma unroll
        for (int mf = 0; mf < 4; ++mf)
#pragma unroll
            for (int rg = 0; rg < 4; ++rg) {
                float v = acc[mf][nf][rg] + bs[nf];
                s += v; ss += v * v;
            }
        red_stats(s, ss);
        if (quad == 0 && (nl & 7) == 0) sred[wid][nf * 2 + (nl >> 3)] = make_float2(s, ss);
    }

    __syncthreads();
#pragma unroll
    for (int mf = 0; mf < 4; ++mf)
#pragma unroll
        for (int nf = 0; nf < NF; ++nf)
#pragma unroll
            for (int rg = 0; rg < 4; ++rg) {
                int px = wid * 64 + mf * 16 + quad * 4 + rg;
                lE[px * EP + nf * 16 + nl] = f2bf(acc[mf][nf][rg] + bs[nf]);
            }
    __syncthreads();
#pragma unroll
    for (int it = 0; it < 8; ++it) {
        int idx = it * 256 + tid;
        int px = idx >> 3, ck = idx & 7;
        int row = px >> 6, col = px & 63;
        uint4 v = *(const uint4*)&lE[px * EP + ck * 8];
        *(uint4*)(outp + ((((size_t)(b * 2 + nb) * 64 + h0 + row) * 64 + col) * 64 + ck * 8)) = v;
    }
    if (tid < 8) {
        float2 t0 = sred[0][tid], t1 = sred[1][tid], t2 = sred[2][tid], t3 = sred[3][tid];
        pstats_out[((size_t)b * 16 + (n0 >> 3) + tid) * 16 + ht] =
            make_float2(t0.x + t1.x + t2.x + t3.x, t0.y + t1.y + t2.y + t3.y);
    }
}

// ---------------------------------------------------------------------------
// ConvTranspose 4x4 s2 p1 (input GN4 fused), 4 output-parity phases, XCD-swizzled.
// in A4 blocked [16,2,64,64,64] -> out A5 [16,128,128,64]
// ---------------------------------------------------------------------------
__global__ __launch_bounds__(256, 2) void convt_mfma(const ushort_t* __restrict__ in,
                                                     const ushort_t* __restrict__ wp,
                                                     const float* __restrict__ bias,
                                                     ushort_t* __restrict__ outp,
                                                     float2* __restrict__ pstats_out,
                                                     const float2* __restrict__ pstats_in,
                                                     const float* __restrict__ gamma,
                                                     const float* __restrict__ beta,
                                                     float invC) {
    constexpr int CIN = 128, COUT = 64, NT = 64, NF = 4;
    constexpr int IW = 66, NRI = 5;
    constexpr int AITER = NRI * IW * 4;
    constexpr int CA = 6;
    constexpr int EP = NT + 8;
    constexpr int ASZ = NRI * IW * PAD;
    constexpr int SMEM = (ASZ > 256 * EP) ? ASZ : 256 * EP;
    __shared__ ushort_t smem[SMEM];
    __shared__ float2 sred[4][8];
    __shared__ float2 sshare[CIN];
    ushort_t* lA = smem;
    ushort_t* lE = smem;

    int bid = blockIdx.x;
    int xcd = bid & 7;
    int rest = bid >> 3;
    int half = rest >> 6;
    int local = rest & 63;
    int b = xcd + 8 * half;
    int ht = local & 15;
    int ph = local >> 4;
    int eh = ph >> 1, ew = ph & 1;
    int ho0 = ht * 4;
    int tid = threadIdx.x;
    int lane = tid & 63, wid = tid >> 6;
    int nl = lane & 15, quad = lane >> 4, ql = quad * 8;

    fill_ss<CIN, 16>(sshare, pstats_in, gamma, beta, b, invC, tid);
    __syncthreads();

    int ga[CA], la[CA], pr[CA];
#pragma unroll
    for (int r = 0; r < CA; ++r) {
        int i = tid + r * 256;
        ga[r] = -1; la[r] = 0; pr[r] = 0;
        if (i < AITER) {
            int tr = i / (IW * 4); int rem = i - tr * (IW * 4);
            int p = rem >> 2, part = rem & 3;
            la[r] = (tr * IW + p) * PAD + part * 8;
            pr[r] = part;
            int ih = ho0 + tr - (1 - eh), iw = p - 1;
            if ((unsigned)ih < 64u && (unsigned)iw < 64u)
                ga[r] = (ih * 64 + iw) * 64 + part * 8;
        }
    }

    f32x4 acc[4][NF];
#pragma unroll
    for (int mf = 0; mf < 4; ++mf)
#pragma unroll
        for (int nf = 0; nf < NF; ++nf)
            acc[mf][nf] = (f32x4){0.f, 0.f, 0.f, 0.f};

    uint4 ra[CA];

    auto loadA = [&](int cib) {
        const int blk = cib >> 1;
        const int inner = (cib & 1) * 32;
        const ushort_t* base = in + ((size_t)(b * 2 + blk) * 4096) * 64 + inner;
#pragma unroll
        for (int r = 0; r < CA; ++r) {
            uint4 v = make_uint4(0, 0, 0, 0);
            if (ga[r] >= 0) {
                v = *(const uint4*)(base + ga[r]);
                v = gn8(v, &sshare[cib * 32 + pr[r] * 8]);
            }
            ra[r] = v;
        }
    };

    loadA(0);
    const ushort_t* wlane = wp + ((size_t)ph * 4) * 4 * COUT * 32 + (size_t)nl * 32 + ql;

    for (int cib = 0; cib < 4; ++cib) {
        __syncthreads();
#pragma unroll
        for (int r = 0; r < CA; ++r)
            if (tid + r * 256 < AITER) *(uint4*)&lA[la[r]] = ra[r];
        __syncthreads();
        if (cib + 1 < 4) loadA(cib + 1);

        const ushort_t* wc = wlane + (size_t)cib * 4 * COUT * 32;
        short8 bfc[NF], bfn[NF];
#pragma unroll
        for (int nf = 0; nf < NF; ++nf)
            bfc[nf] = *(const short8*)(wc + nf * 512);

#pragma unroll
        for (int tap = 0; tap < 4; ++tap) {
            const int rs = tap >> 1, cs = tap & 1;
            if (tap < 3) {
#pragma unroll
                for (int nf = 0; nf < NF; ++nf)
                    bfn[nf] = *(const short8*)(wc + (size_t)(tap + 1) * COUT * 32 + nf * 512);
            }
            short8 af[4];
#pragma unroll
            for (int mf = 0; mf < 4; ++mf)
                af[mf] = *(const short8*)&lA[((wid + rs) * IW + mf * 16 + nl + cs + ew) * PAD + ql];
#pragma unroll
            for (int mf = 0; mf < 4; ++mf)
#pragma unroll
                for (int nf = 0; nf < NF; ++nf)
                    acc[mf][nf] = __builtin_amdgcn_mfma_f32_16x16x32_bf16(
                        af[mf], bfc[nf], acc[mf][nf], 0, 0, 0);
#pragma unroll
            for (int nf = 0; nf < NF; ++nf) bfc[nf] = bfn[nf];
        }
    }

    float bs[NF];
#pragma unroll
    for (int nf = 0; nf < NF; ++nf) bs[nf] = bias[nf * 16 + nl];
#pragma unroll
    for (int nf = 0; nf < NF; ++nf) {
        float s = 0.f, ss = 0.f;
#pragma unroll
        for (int mf = 0; mf < 4; ++mf)
#pragma unroll
            for (int rg = 0; rg < 4; ++rg) {
                float v = acc[mf][nf][rg] + bs[nf];
                s += v; ss += v * v;
            }
        red_stats(s, ss);
        if (quad == 0 && (nl & 7) == 0) sred[wid][nf * 2 + (nl >> 3)] = make_float2(s, ss);
    }

    __syncthreads();
#pragma unroll
    for (int mf = 0; mf < 4; ++mf)
#pragma unroll
        for (int nf = 0; nf < NF; ++nf)
#pragma unroll
            for (int rg = 0; rg < 4; ++rg) {
                int px = wid * 64 + mf * 16 + quad * 4 + rg;
                lE[px * EP + nf * 16 + nl] = f2bf(acc[mf][nf][rg] + bs[nf]);
            }
    __syncthreads();
#pragma unroll
    for (int it = 0; it < 8; ++it) {
        int idx = it * 256 + tid;
        int px = idx >> 3, ck = idx & 7;
        int row = px >> 6, wo = px & 63;
        int oh = 2 * (ho0 + row) + eh;
        uint4 v = *(const uint4*)&lE[px * EP + ck * 8];
        *(uint4*)(outp + (((size_t)b * 128 + oh) * 128 + 2 * wo + ew) * 64 + ck * 8) = v;
    }
    if (tid < 8) {
        float2 t0 = sred[0][tid], t1 = sred[1][tid], t2 = sred[2][tid], t3 = sred[3][tid];
        pstats_out[((size_t)b * 8 + tid) * 64 + (ht * 4 + ph)] =
            make_float2(t0.x + t1.x + t2.x + t3.x, t0.y + t1.y + t2.y + t3.y);
    }
}

// ---------------------------------------------------------------------------
extern "C" void kernel_launch(void* const* d_in, const int* in_sizes, int n_in,
                              void* d_out, int out_size, void* d_ws, size_t ws_size,
                              hipStream_t stream) {
    const float* x   = (const float*)d_in[0];
    const float* Kd  = (const float*)d_in[1];
    const float* Kr  = (const float*)d_in[2];
    const float* W1  = (const float*)d_in[3];  const float* b1  = (const float*)d_in[4];
    const float* g1  = (const float*)d_in[5];  const float* be1 = (const float*)d_in[6];
    const float* W2  = (const float*)d_in[7];  const float* b2  = (const float*)d_in[8];
    const float* g2  = (const float*)d_in[9];  const float* be2 = (const float*)d_in[10];
    const float* W3  = (const float*)d_in[11]; const float* b3  = (const float*)d_in[12];
    const float* g3  = (const float*)d_in[13]; const float* be3 = (const float*)d_in[14];
    const float* W4  = (const float*)d_in[15]; const float* b4  = (const float*)d_in[16];
    const float* g4  = (const float*)d_in[17]; const float* be4 = (const float*)d_in[18];
    const float* Wt  = (const float*)d_in[19]; const float* bt  = (const float*)d_in[20];
    const float* g5  = (const float*)d_in[21]; const float* be5 = (const float*)d_in[22];
    const float* W6  = (const float*)d_in[23]; const float* b6  = (const float*)d_in[24];

    ushort_t* U  = (ushort_t*)d_ws;
    ushort_t* V  = U + 8388608;
    ushort_t* WP = V + 16777216;
    ushort_t* wp1 = WP;
    ushort_t* wp2 = WP + 18432;
    ushort_t* wp3 = WP + 149504;
    ushort_t* wp4 = WP + 444416;
    ushort_t* wpt = WP + 739328;
    ushort_t* wp6 = WP + 870400;
    float2* PS = (float2*)(WP + 879616);
    float2* P1 = PS;           // conv1: 16*8*64  = 8192
    float2* P2 = PS + 8192;    // conv2: 16*16*16 = 4096
    float2* P3 = PS + 12288;   // conv3: 16*32*16 = 8192
    float2* P4 = PS + 20480;   // conv4: 16*16*16 = 4096
    float2* P5 = PS + 24576;   // convT: 16*8*64  = 8192
    float* out = (float*)d_out;

    pack_all<<<3436, 256, 0, stream>>>(W1, W2, W3, W4, Wt, W6, WP);

    // DWT: x -> U (A0 [16,128,128,32])
    dwt_nhwc<<<1024, 256, 0, stream>>>(x, Kd, U);

    // conv1 32->64 @128x128: U -> V (A1 [16,128,128,64]), partials P1
    conv_mfma<32, 64, 128, 128, true, false, 16>
        <<<1024, 256, 0, stream>>>(U, wp1, b1, V, P1, nullptr, nullptr, nullptr, 0.f);

    // conv2 (parity, GN1 in) 64->128 s2: V -> U (A2 [16,2,64,64,64]), partials P2
    conv2p_mfma<<<512, 256, 0, stream>>>(V, wp2, b2, U, P2,
                                         P1, g1, be1, 1.f / 131072.f);

    // conv3 (GN2 in) 128->256 @64x64: U -> V (A3 [16,4,64,64,64]), partials P3
    conv_mfma<128, 256, 64, 64, true, true, 16>
        <<<1024, 256, 0, stream>>>(U, wp3, b3, V, P3,
                                   P2, g2, be2, 1.f / 32768.f);

    // conv4 (GN3 in) 256->128 @64x64: V -> U (A4 [16,2,64,64,64]), partials P4
    conv_mfma<256, 128, 64, 64, true, true, 16>
        <<<512, 256, 0, stream>>>(V, wp4, b4, U, P4,
                                  P3, g3, be3, 1.f / 32768.f);

    // convT (GN4 in) 128->64 x2: U -> V (A5 [16,128,128,64]), partials P5
    convt_mfma<<<1024, 256, 0, stream>>>(U, wpt, bt, V, P5,
                                         P4, g4, be4, 1.f / 32768.f);

    // conv6 (GN5 in) 64->16 @128x128: V -> U (A6 [16,128,128,16])
    conv_mfma<64, 16, 128, 128, false, true, 64>
        <<<1024, 256, 0, stream>>>(V, wp6, b6, U, nullptr,
                                   P5, g5, be5, 1.f / 131072.f);

    // IDWT: U -> out
    idwt_nhwc<<<1024, 256, 0, stream>>>(U, Kr, out);
}